// Round 2
// baseline (652.717 us; speedup 1.0000x reference)
//
#include <hip/hip_runtime.h>
#include <hip/hip_bf16.h>

// MultiHeadAttention: B=8, L=1024, D=1024, H=16, dh=64. fp32 in/out.
// Round 8: attn overhaul — (a) XCD-locality grid remap (8 q-tiles of a
// head-slab share one XCD's L2), (b) K reg-prefetch + ds_write_b128 staging
// (no exposed HBM latency at the compute barrier), (c) granule-XOR LDS
// layouts for K/V^T/P (bank-conflict-free b128 reads, no pads, LDS 51200B,
// 3 blocks/CU). GEMMs unchanged from round 7 (256^2 8-phase).
//
// Pipeline (6 launches):
//  1) cvt_w: Wq,Wk,Wv,Wo fp32 -> bf16 (8 MB in ws)
//  2) cvt_a: query,key,value fp32 -> bf16 (48 MB in ws)
//  3) gemm8p<true>  grid(32,4,3): 8-phase GEMM -> q/k/v (bf16, +bias)
//  4) attn grid(8,128): ctx written in-place over qbuf
//  5) gemm8p<false> grid(32,4,1): ctx @ Wo^T + bo -> obuf (fp32)
//  6) ln: LayerNorm(query + O) -> d_out
// ws: qbuf[0,16M) kbuf[16,32M) vbuf[32,48M) W4[48,56M) obuf[16,48M)
//     abuf[56,104M).  Fallback if ws < 104MB: old fp32-A gemm_qkv, no cvt_a.

typedef __bf16 bf16x8 __attribute__((ext_vector_type(8)));
typedef float  f32x4  __attribute__((ext_vector_type(4)));

#define KK 1024
#define NN 1024

union BfPack4 { __bf16 h[4]; uint2 u; };
union BfPack8 { __bf16 h[8]; uint4 u; };

// async global->LDS, 16 B/lane. LDS dest = wave-uniform base + lane*16.
__device__ __forceinline__ void lds_copy16(void* lds, const void* gsrc) {
  __builtin_amdgcn_global_load_lds(
      (__attribute__((address_space(1))) void*)(uintptr_t)gsrc,
      (__attribute__((address_space(3))) void*)(unsigned int)(uintptr_t)lds,
      16, 0, 0);
}

// ---------------------------------------------------------------- converts
struct Cvt4 { const float* src[4]; __bf16* dst; };

__global__ __launch_bounds__(256) void cvt_w(Cvt4 a) {
  const int z = blockIdx.y;
  const float* s = a.src[z];
  __bf16* d = a.dst + (size_t)z * (KK * NN);
  const int i = (blockIdx.x * 256 + threadIdx.x) * 4;
  float4 f = *(const float4*)&s[i];
  BfPack4 p;
  p.h[0] = (__bf16)f.x; p.h[1] = (__bf16)f.y;
  p.h[2] = (__bf16)f.z; p.h[3] = (__bf16)f.w;
  *(uint2*)&d[i] = p.u;
}

struct Cvt3 { const float* src[3]; __bf16* dst; };

__global__ __launch_bounds__(256) void cvt_a(Cvt3 a) {
  const int z = blockIdx.y;
  const float* s = a.src[z];
  __bf16* d = a.dst + (size_t)z * ((size_t)8 << 20);   // 8M elems each
  const size_t i = ((size_t)blockIdx.x * 256 + threadIdx.x) * 8;
  float4 f0 = *(const float4*)&s[i];
  float4 f1 = *(const float4*)&s[i + 4];
  BfPack8 p;
  p.h[0] = (__bf16)f0.x; p.h[1] = (__bf16)f0.y;
  p.h[2] = (__bf16)f0.z; p.h[3] = (__bf16)f0.w;
  p.h[4] = (__bf16)f1.x; p.h[5] = (__bf16)f1.y;
  p.h[6] = (__bf16)f1.z; p.h[7] = (__bf16)f1.w;
  *(uint4*)&d[i] = p.u;
}

// --------------------------------------------- 256x256 8-phase bf16 GEMM
struct G8 {
  const __bf16* A[3];
  const __bf16* W[3];
  const float*  bias[3];
  void*         C[3];
};

#define BAR()   __builtin_amdgcn_s_barrier()
#define PRIO(x) __builtin_amdgcn_s_setprio(x)
#define WAIT_LGKM0() do { asm volatile("s_waitcnt lgkmcnt(0)" ::: "memory"); \
                          __builtin_amdgcn_sched_barrier(0); } while (0)
#define WAIT_VM4()  asm volatile("s_waitcnt vmcnt(4)" ::: "memory")
#define WAIT_VM0()  asm volatile("s_waitcnt vmcnt(0)" ::: "memory")

#define STAGE_A(buf, half, kt) do {                                          \
  lds_copy16(smem + (buf)*32768 + (half)*16384 + ldsW,                       \
             pA0[half] + (size_t)(kt)*64);                                   \
  lds_copy16(smem + (buf)*32768 + (half)*16384 + ldsW + 1024,                \
             pA1[half] + (size_t)(kt)*64); } while (0)

#define STAGE_B(buf, half, kt) do {                                          \
  lds_copy16(smem + 65536 + (buf)*32768 + (half)*16384 + ldsW,               \
             pB0[half] + (size_t)(kt)*64);                                   \
  lds_copy16(smem + 65536 + (buf)*32768 + (half)*16384 + ldsW + 1024,        \
             pB1[half] + (size_t)(kt)*64); } while (0)

#define LDA(buf, mh) do {                                                    \
  const char* _p = aSelf + (buf)*32768 + (mh)*8192;                          \
  _Pragma("unroll") for (int i_ = 0; i_ < 4; ++i_) {                         \
    af[i_][0] = *(const bf16x8*)(_p + i_*2048 + c0_);                        \
    af[i_][1] = *(const bf16x8*)(_p + i_*2048 + c1_); } } while (0)

#define LDB(buf, nh) do {                                                    \
  const char* _p = bSelf + (buf)*32768 + (nh)*4096;                          \
  _Pragma("unroll") for (int j_ = 0; j_ < 2; ++j_) {                         \
    bf[(nh)*2 + j_][0] = *(const bf16x8*)(_p + j_*2048 + c0_);               \
    bf[(nh)*2 + j_][1] = *(const bf16x8*)(_p + j_*2048 + c1_); } } while (0)

#define MM(mh, nh) do {                                                      \
  _Pragma("unroll") for (int i_ = 0; i_ < 4; ++i_)                           \
  _Pragma("unroll") for (int j_ = 0; j_ < 2; ++j_) {                         \
    acc[(mh)*4+i_][(nh)*2+j_] = __builtin_amdgcn_mfma_f32_16x16x32_bf16(     \
        af[i_][0], bf[(nh)*2+j_][0], acc[(mh)*4+i_][(nh)*2+j_], 0, 0, 0);    \
    acc[(mh)*4+i_][(nh)*2+j_] = __builtin_amdgcn_mfma_f32_16x16x32_bf16(     \
        af[i_][1], bf[(nh)*2+j_][1], acc[(mh)*4+i_][(nh)*2+j_], 0, 0, 0);    \
  } } while (0)

template <bool OUT_BF16>
__global__ __launch_bounds__(512, 2) void gemm8p(G8 args)
{
  __shared__ __align__(16) char smem[131072];
  const int z = blockIdx.z;
  const __bf16* __restrict__ A    = args.A[z];
  const __bf16* __restrict__ W    = args.W[z];
  const float*  __restrict__ bias = args.bias[z];

  const int tid = threadIdx.x;
  const int l = tid & 63, w = tid >> 6;
  const int lr = l & 15, lq = l >> 4;
  const int wr = w >> 2, wc = w & 3;          // 2M x 4N waves

  // XCD-aware swizzle over the 128 (m,n) tiles (128 % 8 == 0 -> bijective)
  int lin = blockIdx.y * 32 + blockIdx.x;
  lin = (lin & 7) * 16 + (lin >> 3);
  const int m0 = (lin & 31) * 256;
  const int n0 = (lin >> 5) * 256;

  // staging: thread covers 16B slots s0,s1 of each half-tile; the global
  // source is pre-swizzled so LDS slot row*8+kq holds logical kq^(row&7).
  const int s0 = w * 128 + l, s1 = s0 + 64;
  const int r0 = s0 >> 3, kq0 = (s0 & 7) ^ (r0 & 7);
  const int r1 = s1 >> 3, kq1 = (s1 & 7) ^ (r1 & 7);
  const __bf16* pA0[2]; const __bf16* pA1[2];
  const __bf16* pB0[2]; const __bf16* pB1[2];
  #pragma unroll
  for (int h = 0; h < 2; ++h) {
    pA0[h] = A + (size_t)(m0 + h * 128 + r0) * KK + kq0 * 8;
    pA1[h] = A + (size_t)(m0 + h * 128 + r1) * KK + kq1 * 8;
    pB0[h] = W + (size_t)(n0 + h * 128 + r0) * KK + kq0 * 8;
    pB1[h] = W + (size_t)(n0 + h * 128 + r1) * KK + kq1 * 8;
  }
  const int ldsW = w * 2048;

  // ds_read addressing (same XOR on the read side)
  const int aRow = lr * 128;
  const int c0_ = ((lq)     ^ (lr & 7)) * 16;
  const int c1_ = ((4 + lq) ^ (lr & 7)) * 16;
  const char* aSelf = smem + wr * 16384 + aRow;
  const char* bSelf = smem + 65536 + (wc >> 1) * 16384 + (wc & 1) * 8192 + aRow;

  bf16x8 af[4][2], bf[4][2];
  f32x4 acc[8][4] = {};

  // prologue: tile0 fully, tile1 B halves; drain tile0, keep tile1-B in flight
  STAGE_A(0, 0, 0); STAGE_A(0, 1, 0);
  STAGE_B(0, 0, 0); STAGE_B(0, 1, 0);
  STAGE_B(1, 0, 1); STAGE_B(1, 1, 1);
  WAIT_VM4();
  BAR();

  for (int it = 0; it < 8; ++it) {
    const int t2 = it * 2;
    // ---- P1: Q(0,0) of tile t (buf0); stage A0(t+1)->buf1 ----
    LDA(0, 0); LDB(0, 0);
    STAGE_A(1, 0, t2 + 1);
    BAR(); WAIT_LGKM0();
    PRIO(1); MM(0, 0); PRIO(0);
    BAR();
    // ---- P2: Q(0,1); stage A1(t+1) ----
    LDB(0, 1);
    STAGE_A(1, 1, t2 + 1);
    BAR(); WAIT_LGKM0();
    PRIO(1); MM(0, 1); PRIO(0);
    BAR();
    // ---- P3: Q(1,0); stage B0(t+2)->buf0 (B buf0 free after P2) ----
    LDA(0, 1);
    if (it < 7) STAGE_B(0, 0, t2 + 2);
    BAR(); WAIT_LGKM0();
    PRIO(1); MM(1, 0); PRIO(0);
    BAR();
    // ---- P4: Q(1,1); stage B1(t+2); drain so tile t+1 is fully landed ----
    if (it < 7) { STAGE_B(0, 1, t2 + 2); WAIT_VM4(); }
    else        { WAIT_VM0(); }
    BAR();
    PRIO(1); MM(1, 1); PRIO(0);
    BAR();
    // ---- P5: Q(0,0) of tile t+1 (buf1); stage A0(t+2)->buf0 ----
    LDA(1, 0); LDB(1, 0);
    if (it < 7) STAGE_A(0, 0, t2 + 2);
    BAR(); WAIT_LGKM0();
    PRIO(1); MM(0, 0); PRIO(0);
    BAR();
    // ---- P6: Q(0,1); stage A1(t+2) ----
    LDB(1, 1);
    if (it < 7) STAGE_A(0, 1, t2 + 2);
    BAR(); WAIT_LGKM0();
    PRIO(1); MM(0, 1); PRIO(0);
    BAR();
    // ---- P7: Q(1,0); stage B0(t+3)->buf1 (B buf1 free after P6) ----
    LDA(1, 1);
    if (it < 7) STAGE_B(1, 0, t2 + 3);
    BAR(); WAIT_LGKM0();
    PRIO(1); MM(1, 0); PRIO(0);
    BAR();
    // ---- P8: Q(1,1); stage B1(t+3); drain so tile t+2 is fully landed ----
    if (it < 7) { STAGE_B(1, 1, t2 + 3); WAIT_VM4(); }
    BAR();
    PRIO(1); MM(1, 1); PRIO(0);
    BAR();
  }

  float bv[4];
  #pragma unroll
  for (int n = 0; n < 4; ++n) bv[n] = bias[n0 + wc * 64 + n * 16 + lr];

  #pragma unroll
  for (int f = 0; f < 8; ++f) {
    const int gm = m0 + wr * 128 + f * 16 + lq * 4;
    #pragma unroll
    for (int n = 0; n < 4; ++n) {
      const int gn = n0 + wc * 64 + n * 16 + lr;
      #pragma unroll
      for (int i = 0; i < 4; ++i) {
        const float v = acc[f][n][i] + bv[n];
        if constexpr (OUT_BF16)
          ((__bf16*)args.C[z])[(size_t)(gm + i) * NN + gn] = (__bf16)v;
        else
          ((float*)args.C[z])[(size_t)(gm + i) * NN + gn] = v;
      }
    }
  }
}

// ------------------------------------- fallback fp32-A QKV GEMM (old path)
struct GQKV {
  const float*  A[3];
  const __bf16* W;
  const float*  bias[3];
  __bf16*       C[3];
};

__global__ __launch_bounds__(256) void gemm_qkv(GQKV args)
{
  __shared__ alignas(16) __bf16 As[128 * 40];
  __shared__ alignas(16) __bf16 Bs[2][4096];
  const int z = blockIdx.z;
  const float*  A    = args.A[z];
  const __bf16* W    = args.W + (size_t)z * KK * NN;
  const float*  bias = args.bias[z];
  __bf16* C = args.C[z];
  const int tid = threadIdx.x, l = tid & 63, w = tid >> 6;
  const int m0 = blockIdx.x * 128, n0 = blockIdx.y * 128;
  const int lr = l & 15, lq = l >> 4;
  const int wm = (w & 1) * 64, wn = (w >> 1) * 64;

  const __bf16* gw0 = &W[(size_t)(n0 + (tid >> 2)) * KK + (tid & 3) * 8];
  const __bf16* gw1 = &W[(size_t)(n0 + 64 + (tid >> 2)) * KK + (tid & 3) * 8];

  float4 pa[4];
  #pragma unroll
  for (int s = 0; s < 4; ++s) {
    int c = tid + 256 * s; int row = c >> 3, ko = (c & 7) * 4;
    pa[s] = *(const float4*)&A[(size_t)(m0 + row) * KK + ko];
  }
  lds_copy16((char*)Bs + w * 1024,        gw0);
  lds_copy16((char*)Bs + 4096 + w * 1024, gw1);

  f32x4 acc[4][4] = {};
  int ib = 0;
  for (int kk = 0; kk < KK; kk += 32) {
    __syncthreads();
    #pragma unroll
    for (int s = 0; s < 4; ++s) {
      int c = tid + 256 * s; int row = c >> 3, ko = (c & 7) * 4;
      BfPack4 p;
      p.h[0] = (__bf16)pa[s].x; p.h[1] = (__bf16)pa[s].y;
      p.h[2] = (__bf16)pa[s].z; p.h[3] = (__bf16)pa[s].w;
      *(uint2*)&As[row * 40 + ko] = p.u;
    }
    __syncthreads();
    if (kk + 32 < KK) {
      lds_copy16((char*)Bs + (ib ^ 1) * 8192 + w * 1024,        gw0 + kk + 32);
      lds_copy16((char*)Bs + (ib ^ 1) * 8192 + 4096 + w * 1024, gw1 + kk + 32);
      #pragma unroll
      for (int s = 0; s < 4; ++s) {
        int c = tid + 256 * s; int row = c >> 3, ko = (c & 7) * 4;
        pa[s] = *(const float4*)&A[(size_t)(m0 + row) * KK + kk + 32 + ko];
      }
    }
    const __bf16* Bb = (const __bf16*)((char*)Bs + ib * 8192);
    bf16x8 af2[4], bf2[4];
    #pragma unroll
    for (int t = 0; t < 4; ++t) {
      af2[t] = *(const bf16x8*)&As[(wm + t * 16 + lr) * 40 + lq * 8];
      bf2[t] = *(const bf16x8*)&Bb[(wn + t * 16 + lr) * 32 + lq * 8];
    }
    #pragma unroll
    for (int mt = 0; mt < 4; ++mt)
      #pragma unroll
      for (int nt = 0; nt < 4; ++nt)
        acc[mt][nt] = __builtin_amdgcn_mfma_f32_16x16x32_bf16(af2[mt], bf2[nt], acc[mt][nt], 0, 0, 0);
    ib ^= 1;
  }

  #pragma unroll
  for (int mt = 0; mt < 4; ++mt)
    #pragma unroll
    for (int nt = 0; nt < 4; ++nt)
      #pragma unroll
      for (int i = 0; i < 4; ++i) {
        int gm = m0 + wm + mt * 16 + lq * 4 + i;
        int gn = n0 + wn + nt * 16 + lr;
        C[(size_t)gm * NN + gn] = (__bf16)(acc[mt][nt][i] + bias[gn]);
      }
}

// ------------------------------------------------------------- attention
// Block = (q-tile 128, head-slab g); wave w owns q-rows [32w,32w+32).
// Grid remap: the 8 q-tile blocks of slab g land on ONE XCD (K/V L2 reuse).
// K and V both reg-prefetched one tile ahead; staged to LDS right after
// barrier-1 (no exposed HBM latency at barrier-2). All LDS tiles use a
// 16B-granule XOR layout: elem(row,col) at row*RB + (((col>>3)^(row&M))<<4)
// + (col&7)*2 -> b128 frag reads are bank-conflict-free (uniform 8/bank).
__global__ __launch_bounds__(256, 3) void attn_kernel(
    const __bf16* __restrict__ qb, const __bf16* __restrict__ kb,
    const __bf16* __restrict__ vb, const float* __restrict__ qm,
    const float* __restrict__ km, __bf16* __restrict__ ctxb)
{
  // XCD-locality: xcd = linear%8 = blockIdx.x; 16 slabs per XCD.
  const int g  = blockIdx.x * 16 + (blockIdx.y >> 3);   // 0..127
  const int qt = blockIdx.y & 7;                        // 0..7
  const int tid = threadIdx.x, l = tid & 63, w = tid >> 6;
  const int lr = l & 15, lq = l >> 4;

  __shared__ alignas(16) __bf16 Ps[128 * 64];      // P (XOR, M=7); Q prologue
  __shared__ alignas(16) __bf16 Ks[2 * 128 * 32];  // K panels (XOR, M=3)
  __shared__ alignas(16) __bf16 Vt[64 * 128];      // V^T (XOR, M=15)
  __shared__ alignas(16) __bf16 kms[1024];         // k-mask gate bits

  const size_t gbase = (size_t)g * (1024 * 64);
  const __bf16* qg = qb + gbase;
  const __bf16* kg = kb + gbase;
  const __bf16* vg = vb + gbase;
  const float* qmrow = qm + (size_t)(g & 7) * 1024;
  const float* kmrow = km + (size_t)(g & 7) * 1024;

  // ---- prologue ----
  #pragma unroll
  for (int s = 0; s < 4; ++s) {               // Q 128x64 async into Ps region
    int c = tid + 256 * s;
    int p = c >> 9, r = (c >> 2) & 127, q0 = c & 3;
    lds_copy16((char*)Ps + w * 1024 + s * 4096,
               &qg[(size_t)(qt * 128 + r) * 64 + p * 32 + q0 * 8]);
  }
  {                                           // mask gate bits (nonzero-ness)
    float4 kf = *(const float4*)&kmrow[tid * 4];
    BfPack4 p;
    p.h[0] = (__bf16)(kf.x == 0.f ? 0.f : 1.f);
    p.h[1] = (__bf16)(kf.y == 0.f ? 0.f : 1.f);
    p.h[2] = (__bf16)(kf.z == 0.f ? 0.f : 1.f);
    p.h[3] = (__bf16)(kf.w == 0.f ? 0.f : 1.f);
    *(uint2*)&kms[tid * 4] = p.u;
  }
  float qmv[2][4];
  #pragma unroll
  for (int rt = 0; rt < 2; ++rt)
    #pragma unroll
    for (int i = 0; i < 4; ++i)
      qmv[rt][i] = qmrow[qt * 128 + 32 * w + rt * 16 + lq * 4 + i];

  __syncthreads();

  bf16x8 qa[2][2];                            // Q frags, pinned all 8 iters
  #pragma unroll
  for (int rt = 0; rt < 2; ++rt)
    #pragma unroll
    for (int p = 0; p < 2; ++p)
      qa[rt][p] = *(const bf16x8*)((char*)Ps + p * 8192 +
                                   (32 * w + rt * 16 + lr) * 64 + lq * 16);

  uint4 pk[4], pv[4];                         // K,V reg prefetch (tile 0)
  #pragma unroll
  for (int s = 0; s < 4; ++s) {
    int c = tid + 256 * s; int p = c >> 9, r = (c >> 2) & 127, q0 = c & 3;
    pk[s] = *(const uint4*)&kg[(size_t)r * 64 + p * 32 + q0 * 8];
  }
  #pragma unroll
  for (int s = 0; s < 4; ++s) {
    int ch = tid + 256 * s; int j = ch & 127, c0 = ch >> 7;
    pv[s] = *(const uint4*)&vg[(size_t)j * 64 + c0 * 8];
  }

  const int kKey = (lq ^ (lr & 3)) << 4;      // K read granule offset
  float rs[2][4] = {};
  f32x4 ctx[2][4] = {};

  for (int kt = 0; kt < 8; ++kt) {
    __syncthreads();                          // barrier-1: prev compute done
    #pragma unroll
    for (int s = 0; s < 4; ++s) {             // K panels from regs (b128)
      int c = tid + 256 * s; int p = c >> 9, r = (c >> 2) & 127, q0 = c & 3;
      *(uint4*)((char*)Ks + p * 8192 + r * 64 + ((q0 ^ (r & 3)) << 4)) = pk[s];
    }
    #pragma unroll
    for (int s = 0; s < 4; ++s) {             // V^T from regs (XOR scalar)
      int ch = tid + 256 * s; int j = ch & 127, c0 = ch >> 7;
      BfPack8 vv; vv.u = pv[s];
      const int jhi = (j >> 3) << 4, jlo = (j & 7) * 2;
      #pragma unroll
      for (int cc = 0; cc < 8; ++cc) {
        int row = c0 * 8 + cc;
        *(__bf16*)((char*)Vt + row * 256 + (jhi ^ ((row & 15) << 4)) + jlo) =
            vv.h[cc];
      }
    }
    __syncthreads();                          // barrier-2: staging visible
    if (kt < 7) {                             // prefetch next K,V tiles
      #pragma unroll
      for (int s = 0; s < 4; ++s) {
        int c = tid + 256 * s; int p = c >> 9, r = (c >> 2) & 127, q0 = c & 3;
        pk[s] = *(const uint4*)&kg[(size_t)((kt + 1) * 128 + r) * 64 + p * 32 + q0 * 8];
      }
      #pragma unroll
      for (int s = 0; s < 4; ++s) {
        int ch = tid + 256 * s; int j = ch & 127, c0 = ch >> 7;
        pv[s] = *(const uint4*)&vg[(size_t)((kt + 1) * 128 + j) * 64 + c0 * 8];
      }
    }
    #pragma unroll
    for (int h = 0; h < 2; ++h) {             // two 64-j halves
      f32x4 sacc[2][4];
      #pragma unroll
      for (int c4 = 0; c4 < 4; ++c4) {        // S = Q K^T
        int ct = h * 4 + c4;
        bf16x8 kb0 = *(const bf16x8*)((char*)Ks + (ct * 16 + lr) * 64 + kKey);
        bf16x8 kb1 = *(const bf16x8*)((char*)Ks + 8192 + (ct * 16 + lr) * 64 + kKey);
        #pragma unroll
        for (int rt = 0; rt < 2; ++rt) {
          f32x4 zz = {};
          zz = __builtin_amdgcn_mfma_f32_16x16x32_bf16(qa[rt][0], kb0, zz, 0, 0, 0);
          sacc[rt][c4] = __builtin_amdgcn_mfma_f32_16x16x32_bf16(qa[rt][1], kb1, zz, 0, 0, 0);
        }
      }
      #pragma unroll
      for (int c4 = 0; c4 < 4; ++c4) {        // unnormalized exp + P -> LDS
        int ct = h * 4 + c4;
        float kmv = (float)kms[kt * 128 + ct * 16 + lr];
        #pragma unroll
        for (int rt = 0; rt < 2; ++rt)
          #pragma unroll
          for (int i = 0; i < 4; ++i) {
            float e = (qmv[rt][i] * kmv == 0.f) ? 0.f
                                                : __expf(sacc[rt][c4][i] * 0.125f);
            rs[rt][i] += e;
            int row = 32 * w + rt * 16 + lq * 4 + i;
            *(__bf16*)((char*)Ps + row * 128 +
                       (((c4 * 2 + (lr >> 3)) ^ (row & 7)) << 4) +
                       (lr & 7) * 2) = (__bf16)e;
          }
      }
      #pragma unroll
      for (int ks = 0; ks < 2; ++ks) {        // PV for this half
        bf16x8 pa2[2];
        #pragma unroll
        for (int rt = 0; rt < 2; ++rt) {
          int row = 32 * w + rt * 16 + lr;
          pa2[rt] = *(const bf16x8*)((char*)Ps + row * 128 +
                                     (((ks * 4 + lq) ^ (row & 7)) << 4));
        }
        #pragma unroll
        for (int c2 = 0; c2 < 4; ++c2) {
          int vrow = c2 * 16 + lr;
          bf16x8 vf = *(const bf16x8*)((char*)Vt + vrow * 256 +
                        (((h * 8 + ks * 4 + lq) << 4) ^ ((vrow & 15) << 4)));
          #pragma unroll
          for (int rt = 0; rt < 2; ++rt)
            ctx[rt][c2] = __builtin_amdgcn_mfma_f32_16x16x32_bf16(pa2[rt], vf, ctx[rt][c2], 0, 0, 0);
        }
      }
    }
  }

  #pragma unroll
  for (int rt = 0; rt < 2; ++rt)              // row sums over 16 lr-lanes
    #pragma unroll
    for (int i = 0; i < 4; ++i) {
      float v = rs[rt][i];
      v += __shfl_xor(v, 1);
      v += __shfl_xor(v, 2);
      v += __shfl_xor(v, 4);
      v += __shfl_xor(v, 8);
      rs[rt][i] = 1.0f / fmaxf(v, 2e-15f);    // clip(sum, 2e-15) per reference
    }

  #pragma unroll
  for (int rt = 0; rt < 2; ++rt)
    #pragma unroll
    for (int c2 = 0; c2 < 4; ++c2)
      #pragma unroll
      for (int i = 0; i < 4; ++i) {
        int row = qt * 128 + 32 * w + rt * 16 + lq * 4 + i;
        ctxb[gbase + (size_t)row * 64 + c2 * 16 + lr] =
            (__bf16)(ctx[rt][c2][i] * rs[rt][i]);
      }
}

// ------------------------------------------------------------- layernorm
__global__ __launch_bounds__(256) void ln_kernel(
    const float* __restrict__ O, const float* __restrict__ resid,
    const float* __restrict__ gam, const float* __restrict__ bet,
    float* __restrict__ out)
{
  const int row = blockIdx.x;
  const int tid = threadIdx.x;
  const float* orow = O + (size_t)row * 1024;
  const float* rrow = resid + (size_t)row * 1024;
  float x[4];
  float sum = 0.f, sq = 0.f;
  #pragma unroll
  for (int j = 0; j < 4; ++j) {
    int c = tid + j * 256;
    x[j] = orow[c] + rrow[c];
    sum += x[j];
    sq  += x[j] * x[j];
  }
  #pragma unroll
  for (int off = 32; off > 0; off >>= 1) {
    sum += __shfl_down(sum, off, 64);
    sq  += __shfl_down(sq, off, 64);
  }
  __shared__ float s1[4], s2[4];
  __shared__ float mean_s, inv_s;
  if ((tid & 63) == 0) { s1[tid >> 6] = sum; s2[tid >> 6] = sq; }
  __syncthreads();
  if (tid == 0) {
    float S = s1[0] + s1[1] + s1[2] + s1[3];
    float Q = s2[0] + s2[1] + s2[2] + s2[3];
    float mean = S * (1.0f / 1024.0f);
    float var  = fmaxf(Q * (1.0f / 1024.0f) - mean * mean, 0.0f);
    mean_s = mean;
    inv_s  = rsqrtf(var + 1e-5f);
  }
  __syncthreads();
  float mean = mean_s, inv = inv_s;
  #pragma unroll
  for (int j = 0; j < 4; ++j) {
    int c = tid + j * 256;
    out[(size_t)row * 1024 + c] = (x[j] - mean) * inv * gam[c] + bet[c];
  }
}

extern "C" void kernel_launch(void* const* d_in, const int* in_sizes, int n_in,
                              void* d_out, int out_size, void* d_ws, size_t ws_size,
                              hipStream_t stream)
{
  const float* query = (const float*)d_in[0];
  const float* keyi  = (const float*)d_in[1];
  const float* value = (const float*)d_in[2];
  const float* qmask = (const float*)d_in[3];
  const float* kmask = (const float*)d_in[4];
  const float* Wq = (const float*)d_in[5];
  const float* bq = (const float*)d_in[6];
  const float* Wk = (const float*)d_in[7];
  const float* bk = (const float*)d_in[8];
  const float* Wv = (const float*)d_in[9];
  const float* bv = (const float*)d_in[10];
  const float* Wo = (const float*)d_in[11];
  const float* bo = (const float*)d_in[12];
  const float* gam = (const float*)d_in[13];
  const float* bet = (const float*)d_in[14];

  char* ws = (char*)d_ws;
  __bf16* qbuf = (__bf16*)(ws);
  __bf16* kbuf = (__bf16*)(ws + ((size_t)16 << 20));
  __bf16* vbuf = (__bf16*)(ws + ((size_t)32 << 20));
  __bf16* wb   = (__bf16*)(ws + ((size_t)48 << 20));
  float*  obuf = (float*)(ws + ((size_t)16 << 20));
  __bf16* abuf = (__bf16*)(ws + ((size_t)56 << 20));  // 48 MB, main path only

  const bool big = ws_size >= ((size_t)104 << 20);

  Cvt4 cv;
  cv.src[0] = Wq; cv.src[1] = Wk; cv.src[2] = Wv; cv.src[3] = Wo;
  cv.dst = wb;

  dim3 tb(256);
  hipLaunchKernelGGL(cvt_w, dim3(1024, 4), tb, 0, stream, cv);

  if (big) {
    Cvt3 ca;
    ca.src[0] = query; ca.src[1] = keyi; ca.src[2] = value;
    ca.dst = abuf;
    hipLaunchKernelGGL(cvt_a, dim3(4096, 3), tb, 0, stream, ca);

    G8 gq;
    gq.A[0] = abuf;
    gq.A[1] = abuf + ((size_t)8 << 20);
    gq.A[2] = abuf + ((size_t)16 << 20);
    gq.W[0] = wb; gq.W[1] = wb + (size_t)KK * NN; gq.W[2] = wb + (size_t)2 * KK * NN;
    gq.bias[0] = bq; gq.bias[1] = bk; gq.bias[2] = bv;
    gq.C[0] = qbuf; gq.C[1] = kbuf; gq.C[2] = vbuf;
    hipLaunchKernelGGL((gemm8p<true>), dim3(32, 4, 3), dim3(512), 0, stream, gq);
  } else {
    GQKV qkv;
    qkv.A[0] = query; qkv.A[1] = keyi; qkv.A[2] = value;
    qkv.W = wb;
    qkv.bias[0] = bq; qkv.bias[1] = bk; qkv.bias[2] = bv;
    qkv.C[0] = qbuf;  qkv.C[1] = kbuf; qkv.C[2] = vbuf;
    hipLaunchKernelGGL(gemm_qkv, dim3(64, 8, 3), tb, 0, stream, qkv);
  }

  hipLaunchKernelGGL(attn_kernel, dim3(8, 128), tb, 0, stream,
                     qbuf, kbuf, vbuf, qmask, kmask, qbuf);

  G8 go;
  go.A[0] = qbuf;                      // ctx (bf16, in-place over qbuf)
  go.W[0] = wb + (size_t)3 * KK * NN;  // Wo bf16
  go.bias[0] = bo;
  go.C[0] = obuf;
  go.A[1] = go.A[2] = go.A[0]; go.W[1] = go.W[2] = go.W[0];
  go.bias[1] = go.bias[2] = go.bias[0]; go.C[1] = go.C[2] = go.C[0];
  hipLaunchKernelGGL((gemm8p<false>), dim3(32, 4, 1), dim3(512), 0, stream, go);

  hipLaunchKernelGGL(ln_kernel, dim3(8192), tb, 0, stream,
                     obuf, query, gam, bet, (float*)d_out);
}

// Round 3
// 413.177 us; speedup vs baseline: 1.5798x; 1.5798x over previous
//
#include <hip/hip_runtime.h>
#include <hip/hip_bf16.h>

// MultiHeadAttention: B=8, L=1024, D=1024, H=16, dh=64. fp32 in/out.
// Round 9: fix round-8's spill cliff. __launch_bounds__(256,3) on attn
// capped the allocator at 84 VGPR -> pk/pv/qa/ctx spilled to scratch
// (WRITE_SIZE 16MB->281MB, dur 135->393us). Reverted to plain
// __launch_bounds__(256) (the 135us config). All round-8 algorithmic
// changes kept: XCD-locality grid remap, K+V reg-prefetch staging,
// granule-XOR conflict-free LDS layouts (bank conflicts 6.4M->2.2M).
//
// Pipeline (6 launches):
//  1) cvt_w: Wq,Wk,Wv,Wo fp32 -> bf16 (8 MB in ws)
//  2) cvt_a: query,key,value fp32 -> bf16 (48 MB in ws)
//  3) gemm8p<true>  grid(32,4,3): 8-phase GEMM -> q/k/v (bf16, +bias)
//  4) attn grid(8,128): ctx written in-place over qbuf
//  5) gemm8p<false> grid(32,4,1): ctx @ Wo^T + bo -> obuf (fp32)
//  6) ln: LayerNorm(query + O) -> d_out
// ws: qbuf[0,16M) kbuf[16,32M) vbuf[32,48M) W4[48,56M) obuf[16,48M)
//     abuf[56,104M).  Fallback if ws < 104MB: old fp32-A gemm_qkv, no cvt_a.

typedef __bf16 bf16x8 __attribute__((ext_vector_type(8)));
typedef float  f32x4  __attribute__((ext_vector_type(4)));

#define KK 1024
#define NN 1024

union BfPack4 { __bf16 h[4]; uint2 u; };
union BfPack8 { __bf16 h[8]; uint4 u; };

// async global->LDS, 16 B/lane. LDS dest = wave-uniform base + lane*16.
__device__ __forceinline__ void lds_copy16(void* lds, const void* gsrc) {
  __builtin_amdgcn_global_load_lds(
      (__attribute__((address_space(1))) void*)(uintptr_t)gsrc,
      (__attribute__((address_space(3))) void*)(unsigned int)(uintptr_t)lds,
      16, 0, 0);
}

// ---------------------------------------------------------------- converts
struct Cvt4 { const float* src[4]; __bf16* dst; };

__global__ __launch_bounds__(256) void cvt_w(Cvt4 a) {
  const int z = blockIdx.y;
  const float* s = a.src[z];
  __bf16* d = a.dst + (size_t)z * (KK * NN);
  const int i = (blockIdx.x * 256 + threadIdx.x) * 4;
  float4 f = *(const float4*)&s[i];
  BfPack4 p;
  p.h[0] = (__bf16)f.x; p.h[1] = (__bf16)f.y;
  p.h[2] = (__bf16)f.z; p.h[3] = (__bf16)f.w;
  *(uint2*)&d[i] = p.u;
}

struct Cvt3 { const float* src[3]; __bf16* dst; };

__global__ __launch_bounds__(256) void cvt_a(Cvt3 a) {
  const int z = blockIdx.y;
  const float* s = a.src[z];
  __bf16* d = a.dst + (size_t)z * ((size_t)8 << 20);   // 8M elems each
  const size_t i = ((size_t)blockIdx.x * 256 + threadIdx.x) * 8;
  float4 f0 = *(const float4*)&s[i];
  float4 f1 = *(const float4*)&s[i + 4];
  BfPack8 p;
  p.h[0] = (__bf16)f0.x; p.h[1] = (__bf16)f0.y;
  p.h[2] = (__bf16)f0.z; p.h[3] = (__bf16)f0.w;
  p.h[4] = (__bf16)f1.x; p.h[5] = (__bf16)f1.y;
  p.h[6] = (__bf16)f1.z; p.h[7] = (__bf16)f1.w;
  *(uint4*)&d[i] = p.u;
}

// --------------------------------------------- 256x256 8-phase bf16 GEMM
struct G8 {
  const __bf16* A[3];
  const __bf16* W[3];
  const float*  bias[3];
  void*         C[3];
};

#define BAR()   __builtin_amdgcn_s_barrier()
#define PRIO(x) __builtin_amdgcn_s_setprio(x)
#define WAIT_LGKM0() do { asm volatile("s_waitcnt lgkmcnt(0)" ::: "memory"); \
                          __builtin_amdgcn_sched_barrier(0); } while (0)
#define WAIT_VM4()  asm volatile("s_waitcnt vmcnt(4)" ::: "memory")
#define WAIT_VM0()  asm volatile("s_waitcnt vmcnt(0)" ::: "memory")

#define STAGE_A(buf, half, kt) do {                                          \
  lds_copy16(smem + (buf)*32768 + (half)*16384 + ldsW,                       \
             pA0[half] + (size_t)(kt)*64);                                   \
  lds_copy16(smem + (buf)*32768 + (half)*16384 + ldsW + 1024,                \
             pA1[half] + (size_t)(kt)*64); } while (0)

#define STAGE_B(buf, half, kt) do {                                          \
  lds_copy16(smem + 65536 + (buf)*32768 + (half)*16384 + ldsW,               \
             pB0[half] + (size_t)(kt)*64);                                   \
  lds_copy16(smem + 65536 + (buf)*32768 + (half)*16384 + ldsW + 1024,        \
             pB1[half] + (size_t)(kt)*64); } while (0)

#define LDA(buf, mh) do {                                                    \
  const char* _p = aSelf + (buf)*32768 + (mh)*8192;                          \
  _Pragma("unroll") for (int i_ = 0; i_ < 4; ++i_) {                         \
    af[i_][0] = *(const bf16x8*)(_p + i_*2048 + c0_);                        \
    af[i_][1] = *(const bf16x8*)(_p + i_*2048 + c1_); } } while (0)

#define LDB(buf, nh) do {                                                    \
  const char* _p = bSelf + (buf)*32768 + (nh)*4096;                          \
  _Pragma("unroll") for (int j_ = 0; j_ < 2; ++j_) {                         \
    bf[(nh)*2 + j_][0] = *(const bf16x8*)(_p + j_*2048 + c0_);               \
    bf[(nh)*2 + j_][1] = *(const bf16x8*)(_p + j_*2048 + c1_); } } while (0)

#define MM(mh, nh) do {                                                      \
  _Pragma("unroll") for (int i_ = 0; i_ < 4; ++i_)                           \
  _Pragma("unroll") for (int j_ = 0; j_ < 2; ++j_) {                         \
    acc[(mh)*4+i_][(nh)*2+j_] = __builtin_amdgcn_mfma_f32_16x16x32_bf16(     \
        af[i_][0], bf[(nh)*2+j_][0], acc[(mh)*4+i_][(nh)*2+j_], 0, 0, 0);    \
    acc[(mh)*4+i_][(nh)*2+j_] = __builtin_amdgcn_mfma_f32_16x16x32_bf16(     \
        af[i_][1], bf[(nh)*2+j_][1], acc[(mh)*4+i_][(nh)*2+j_], 0, 0, 0);    \
  } } while (0)

template <bool OUT_BF16>
__global__ __launch_bounds__(512, 2) void gemm8p(G8 args)
{
  __shared__ __align__(16) char smem[131072];
  const int z = blockIdx.z;
  const __bf16* __restrict__ A    = args.A[z];
  const __bf16* __restrict__ W    = args.W[z];
  const float*  __restrict__ bias = args.bias[z];

  const int tid = threadIdx.x;
  const int l = tid & 63, w = tid >> 6;
  const int lr = l & 15, lq = l >> 4;
  const int wr = w >> 2, wc = w & 3;          // 2M x 4N waves

  // XCD-aware swizzle over the 128 (m,n) tiles (128 % 8 == 0 -> bijective)
  int lin = blockIdx.y * 32 + blockIdx.x;
  lin = (lin & 7) * 16 + (lin >> 3);
  const int m0 = (lin & 31) * 256;
  const int n0 = (lin >> 5) * 256;

  // staging: thread covers 16B slots s0,s1 of each half-tile; the global
  // source is pre-swizzled so LDS slot row*8+kq holds logical kq^(row&7).
  const int s0 = w * 128 + l, s1 = s0 + 64;
  const int r0 = s0 >> 3, kq0 = (s0 & 7) ^ (r0 & 7);
  const int r1 = s1 >> 3, kq1 = (s1 & 7) ^ (r1 & 7);
  const __bf16* pA0[2]; const __bf16* pA1[2];
  const __bf16* pB0[2]; const __bf16* pB1[2];
  #pragma unroll
  for (int h = 0; h < 2; ++h) {
    pA0[h] = A + (size_t)(m0 + h * 128 + r0) * KK + kq0 * 8;
    pA1[h] = A + (size_t)(m0 + h * 128 + r1) * KK + kq1 * 8;
    pB0[h] = W + (size_t)(n0 + h * 128 + r0) * KK + kq0 * 8;
    pB1[h] = W + (size_t)(n0 + h * 128 + r1) * KK + kq1 * 8;
  }
  const int ldsW = w * 2048;

  // ds_read addressing (same XOR on the read side)
  const int aRow = lr * 128;
  const int c0_ = ((lq)     ^ (lr & 7)) * 16;
  const int c1_ = ((4 + lq) ^ (lr & 7)) * 16;
  const char* aSelf = smem + wr * 16384 + aRow;
  const char* bSelf = smem + 65536 + (wc >> 1) * 16384 + (wc & 1) * 8192 + aRow;

  bf16x8 af[4][2], bf[4][2];
  f32x4 acc[8][4] = {};

  // prologue: tile0 fully, tile1 B halves; drain tile0, keep tile1-B in flight
  STAGE_A(0, 0, 0); STAGE_A(0, 1, 0);
  STAGE_B(0, 0, 0); STAGE_B(0, 1, 0);
  STAGE_B(1, 0, 1); STAGE_B(1, 1, 1);
  WAIT_VM4();
  BAR();

  for (int it = 0; it < 8; ++it) {
    const int t2 = it * 2;
    // ---- P1: Q(0,0) of tile t (buf0); stage A0(t+1)->buf1 ----
    LDA(0, 0); LDB(0, 0);
    STAGE_A(1, 0, t2 + 1);
    BAR(); WAIT_LGKM0();
    PRIO(1); MM(0, 0); PRIO(0);
    BAR();
    // ---- P2: Q(0,1); stage A1(t+1) ----
    LDB(0, 1);
    STAGE_A(1, 1, t2 + 1);
    BAR(); WAIT_LGKM0();
    PRIO(1); MM(0, 1); PRIO(0);
    BAR();
    // ---- P3: Q(1,0); stage B0(t+2)->buf0 (B buf0 free after P2) ----
    LDA(0, 1);
    if (it < 7) STAGE_B(0, 0, t2 + 2);
    BAR(); WAIT_LGKM0();
    PRIO(1); MM(1, 0); PRIO(0);
    BAR();
    // ---- P4: Q(1,1); stage B1(t+2); drain so tile t+1 is fully landed ----
    if (it < 7) { STAGE_B(0, 1, t2 + 2); WAIT_VM4(); }
    else        { WAIT_VM0(); }
    BAR();
    PRIO(1); MM(1, 1); PRIO(0);
    BAR();
    // ---- P5: Q(0,0) of tile t+1 (buf1); stage A0(t+2)->buf0 ----
    LDA(1, 0); LDB(1, 0);
    if (it < 7) STAGE_A(0, 0, t2 + 2);
    BAR(); WAIT_LGKM0();
    PRIO(1); MM(0, 0); PRIO(0);
    BAR();
    // ---- P6: Q(0,1); stage A1(t+2) ----
    LDB(1, 1);
    if (it < 7) STAGE_A(0, 1, t2 + 2);
    BAR(); WAIT_LGKM0();
    PRIO(1); MM(0, 1); PRIO(0);
    BAR();
    // ---- P7: Q(1,0); stage B0(t+3)->buf1 (B buf1 free after P6) ----
    LDA(1, 1);
    if (it < 7) STAGE_B(1, 0, t2 + 3);
    BAR(); WAIT_LGKM0();
    PRIO(1); MM(1, 0); PRIO(0);
    BAR();
    // ---- P8: Q(1,1); stage B1(t+3); drain so tile t+2 is fully landed ----
    if (it < 7) { STAGE_B(1, 1, t2 + 3); WAIT_VM4(); }
    BAR();
    PRIO(1); MM(1, 1); PRIO(0);
    BAR();
  }

  float bv[4];
  #pragma unroll
  for (int n = 0; n < 4; ++n) bv[n] = bias[n0 + wc * 64 + n * 16 + lr];

  #pragma unroll
  for (int f = 0; f < 8; ++f) {
    const int gm = m0 + wr * 128 + f * 16 + lq * 4;
    #pragma unroll
    for (int n = 0; n < 4; ++n) {
      const int gn = n0 + wc * 64 + n * 16 + lr;
      #pragma unroll
      for (int i = 0; i < 4; ++i) {
        const float v = acc[f][n][i] + bv[n];
        if constexpr (OUT_BF16)
          ((__bf16*)args.C[z])[(size_t)(gm + i) * NN + gn] = (__bf16)v;
        else
          ((float*)args.C[z])[(size_t)(gm + i) * NN + gn] = v;
      }
    }
  }
}

// ------------------------------------- fallback fp32-A QKV GEMM (old path)
struct GQKV {
  const float*  A[3];
  const __bf16* W;
  const float*  bias[3];
  __bf16*       C[3];
};

__global__ __launch_bounds__(256) void gemm_qkv(GQKV args)
{
  __shared__ alignas(16) __bf16 As[128 * 40];
  __shared__ alignas(16) __bf16 Bs[2][4096];
  const int z = blockIdx.z;
  const float*  A    = args.A[z];
  const __bf16* W    = args.W + (size_t)z * KK * NN;
  const float*  bias = args.bias[z];
  __bf16* C = args.C[z];
  const int tid = threadIdx.x, l = tid & 63, w = tid >> 6;
  const int m0 = blockIdx.x * 128, n0 = blockIdx.y * 128;
  const int lr = l & 15, lq = l >> 4;
  const int wm = (w & 1) * 64, wn = (w >> 1) * 64;

  const __bf16* gw0 = &W[(size_t)(n0 + (tid >> 2)) * KK + (tid & 3) * 8];
  const __bf16* gw1 = &W[(size_t)(n0 + 64 + (tid >> 2)) * KK + (tid & 3) * 8];

  float4 pa[4];
  #pragma unroll
  for (int s = 0; s < 4; ++s) {
    int c = tid + 256 * s; int row = c >> 3, ko = (c & 7) * 4;
    pa[s] = *(const float4*)&A[(size_t)(m0 + row) * KK + ko];
  }
  lds_copy16((char*)Bs + w * 1024,        gw0);
  lds_copy16((char*)Bs + 4096 + w * 1024, gw1);

  f32x4 acc[4][4] = {};
  int ib = 0;
  for (int kk = 0; kk < KK; kk += 32) {
    __syncthreads();
    #pragma unroll
    for (int s = 0; s < 4; ++s) {
      int c = tid + 256 * s; int row = c >> 3, ko = (c & 7) * 4;
      BfPack4 p;
      p.h[0] = (__bf16)pa[s].x; p.h[1] = (__bf16)pa[s].y;
      p.h[2] = (__bf16)pa[s].z; p.h[3] = (__bf16)pa[s].w;
      *(uint2*)&As[row * 40 + ko] = p.u;
    }
    __syncthreads();
    if (kk + 32 < KK) {
      lds_copy16((char*)Bs + (ib ^ 1) * 8192 + w * 1024,        gw0 + kk + 32);
      lds_copy16((char*)Bs + (ib ^ 1) * 8192 + 4096 + w * 1024, gw1 + kk + 32);
      #pragma unroll
      for (int s = 0; s < 4; ++s) {
        int c = tid + 256 * s; int row = c >> 3, ko = (c & 7) * 4;
        pa[s] = *(const float4*)&A[(size_t)(m0 + row) * KK + kk + 32 + ko];
      }
    }
    const __bf16* Bb = (const __bf16*)((char*)Bs + ib * 8192);
    bf16x8 af2[4], bf2[4];
    #pragma unroll
    for (int t = 0; t < 4; ++t) {
      af2[t] = *(const bf16x8*)&As[(wm + t * 16 + lr) * 40 + lq * 8];
      bf2[t] = *(const bf16x8*)&Bb[(wn + t * 16 + lr) * 32 + lq * 8];
    }
    #pragma unroll
    for (int mt = 0; mt < 4; ++mt)
      #pragma unroll
      for (int nt = 0; nt < 4; ++nt)
        acc[mt][nt] = __builtin_amdgcn_mfma_f32_16x16x32_bf16(af2[mt], bf2[nt], acc[mt][nt], 0, 0, 0);
    ib ^= 1;
  }

  #pragma unroll
  for (int mt = 0; mt < 4; ++mt)
    #pragma unroll
    for (int nt = 0; nt < 4; ++nt)
      #pragma unroll
      for (int i = 0; i < 4; ++i) {
        int gm = m0 + wm + mt * 16 + lq * 4 + i;
        int gn = n0 + wn + nt * 16 + lr;
        C[(size_t)gm * NN + gn] = (__bf16)(acc[mt][nt][i] + bias[gn]);
      }
}

// ------------------------------------------------------------- attention
// Block = (q-tile 128, head-slab g); wave w owns q-rows [32w,32w+32).
// Grid remap: the 8 q-tile blocks of slab g land on ONE XCD (K/V L2 reuse).
// K and V both reg-prefetched one tile ahead; staged to LDS right after
// barrier-1 (no exposed HBM latency at barrier-2). All LDS tiles use a
// 16B-granule XOR layout: elem(row,col) at row*RB + (((col>>3)^(row&M))<<4)
// + (col&7)*2 -> b128 frag reads are bank-conflict-free (uniform 8/bank).
// NOTE: plain __launch_bounds__(256) — adding a min-occupancy hint here
// capped VGPR at 84 and spilled everything (round-8 post-mortem).
__global__ __launch_bounds__(256) void attn_kernel(
    const __bf16* __restrict__ qb, const __bf16* __restrict__ kb,
    const __bf16* __restrict__ vb, const float* __restrict__ qm,
    const float* __restrict__ km, __bf16* __restrict__ ctxb)
{
  // XCD-locality: xcd = linear%8 = blockIdx.x; 16 slabs per XCD.
  const int g  = blockIdx.x * 16 + (blockIdx.y >> 3);   // 0..127
  const int qt = blockIdx.y & 7;                        // 0..7
  const int tid = threadIdx.x, l = tid & 63, w = tid >> 6;
  const int lr = l & 15, lq = l >> 4;

  __shared__ alignas(16) __bf16 Ps[128 * 64];      // P (XOR, M=7); Q prologue
  __shared__ alignas(16) __bf16 Ks[2 * 128 * 32];  // K panels (XOR, M=3)
  __shared__ alignas(16) __bf16 Vt[64 * 128];      // V^T (XOR, M=15)
  __shared__ alignas(16) __bf16 kms[1024];         // k-mask gate bits

  const size_t gbase = (size_t)g * (1024 * 64);
  const __bf16* qg = qb + gbase;
  const __bf16* kg = kb + gbase;
  const __bf16* vg = vb + gbase;
  const float* qmrow = qm + (size_t)(g & 7) * 1024;
  const float* kmrow = km + (size_t)(g & 7) * 1024;

  // ---- prologue ----
  #pragma unroll
  for (int s = 0; s < 4; ++s) {               // Q 128x64 async into Ps region
    int c = tid + 256 * s;
    int p = c >> 9, r = (c >> 2) & 127, q0 = c & 3;
    lds_copy16((char*)Ps + w * 1024 + s * 4096,
               &qg[(size_t)(qt * 128 + r) * 64 + p * 32 + q0 * 8]);
  }
  {                                           // mask gate bits (nonzero-ness)
    float4 kf = *(const float4*)&kmrow[tid * 4];
    BfPack4 p;
    p.h[0] = (__bf16)(kf.x == 0.f ? 0.f : 1.f);
    p.h[1] = (__bf16)(kf.y == 0.f ? 0.f : 1.f);
    p.h[2] = (__bf16)(kf.z == 0.f ? 0.f : 1.f);
    p.h[3] = (__bf16)(kf.w == 0.f ? 0.f : 1.f);
    *(uint2*)&kms[tid * 4] = p.u;
  }
  float qmv[2][4];
  #pragma unroll
  for (int rt = 0; rt < 2; ++rt)
    #pragma unroll
    for (int i = 0; i < 4; ++i)
      qmv[rt][i] = qmrow[qt * 128 + 32 * w + rt * 16 + lq * 4 + i];

  __syncthreads();

  bf16x8 qa[2][2];                            // Q frags, pinned all 8 iters
  #pragma unroll
  for (int rt = 0; rt < 2; ++rt)
    #pragma unroll
    for (int p = 0; p < 2; ++p)
      qa[rt][p] = *(const bf16x8*)((char*)Ps + p * 8192 +
                                   (32 * w + rt * 16 + lr) * 64 + lq * 16);

  uint4 pk[4], pv[4];                         // K,V reg prefetch (tile 0)
  #pragma unroll
  for (int s = 0; s < 4; ++s) {
    int c = tid + 256 * s; int p = c >> 9, r = (c >> 2) & 127, q0 = c & 3;
    pk[s] = *(const uint4*)&kg[(size_t)r * 64 + p * 32 + q0 * 8];
  }
  #pragma unroll
  for (int s = 0; s < 4; ++s) {
    int ch = tid + 256 * s; int j = ch & 127, c0 = ch >> 7;
    pv[s] = *(const uint4*)&vg[(size_t)j * 64 + c0 * 8];
  }

  const int kKey = (lq ^ (lr & 3)) << 4;      // K read granule offset
  float rs[2][4] = {};
  f32x4 ctx[2][4] = {};

  for (int kt = 0; kt < 8; ++kt) {
    __syncthreads();                          // barrier-1: prev compute done
    #pragma unroll
    for (int s = 0; s < 4; ++s) {             // K panels from regs (b128)
      int c = tid + 256 * s; int p = c >> 9, r = (c >> 2) & 127, q0 = c & 3;
      *(uint4*)((char*)Ks + p * 8192 + r * 64 + ((q0 ^ (r & 3)) << 4)) = pk[s];
    }
    #pragma unroll
    for (int s = 0; s < 4; ++s) {             // V^T from regs (XOR scalar)
      int ch = tid + 256 * s; int j = ch & 127, c0 = ch >> 7;
      BfPack8 vv; vv.u = pv[s];
      const int jhi = (j >> 3) << 4, jlo = (j & 7) * 2;
      #pragma unroll
      for (int cc = 0; cc < 8; ++cc) {
        int row = c0 * 8 + cc;
        *(__bf16*)((char*)Vt + row * 256 + (jhi ^ ((row & 15) << 4)) + jlo) =
            vv.h[cc];
      }
    }
    __syncthreads();                          // barrier-2: staging visible
    if (kt < 7) {                             // prefetch next K,V tiles
      #pragma unroll
      for (int s = 0; s < 4; ++s) {
        int c = tid + 256 * s; int p = c >> 9, r = (c >> 2) & 127, q0 = c & 3;
        pk[s] = *(const uint4*)&kg[(size_t)((kt + 1) * 128 + r) * 64 + p * 32 + q0 * 8];
      }
      #pragma unroll
      for (int s = 0; s < 4; ++s) {
        int ch = tid + 256 * s; int j = ch & 127, c0 = ch >> 7;
        pv[s] = *(const uint4*)&vg[(size_t)((kt + 1) * 128 + j) * 64 + c0 * 8];
      }
    }
    #pragma unroll
    for (int h = 0; h < 2; ++h) {             // two 64-j halves
      f32x4 sacc[2][4];
      #pragma unroll
      for (int c4 = 0; c4 < 4; ++c4) {        // S = Q K^T
        int ct = h * 4 + c4;
        bf16x8 kb0 = *(const bf16x8*)((char*)Ks + (ct * 16 + lr) * 64 + kKey);
        bf16x8 kb1 = *(const bf16x8*)((char*)Ks + 8192 + (ct * 16 + lr) * 64 + kKey);
        #pragma unroll
        for (int rt = 0; rt < 2; ++rt) {
          f32x4 zz = {};
          zz = __builtin_amdgcn_mfma_f32_16x16x32_bf16(qa[rt][0], kb0, zz, 0, 0, 0);
          sacc[rt][c4] = __builtin_amdgcn_mfma_f32_16x16x32_bf16(qa[rt][1], kb1, zz, 0, 0, 0);
        }
      }
      #pragma unroll
      for (int c4 = 0; c4 < 4; ++c4) {        // unnormalized exp + P -> LDS
        int ct = h * 4 + c4;
        float kmv = (float)kms[kt * 128 + ct * 16 + lr];
        #pragma unroll
        for (int rt = 0; rt < 2; ++rt)
          #pragma unroll
          for (int i = 0; i < 4; ++i) {
            float e = (qmv[rt][i] * kmv == 0.f) ? 0.f
                                                : __expf(sacc[rt][c4][i] * 0.125f);
            rs[rt][i] += e;
            int row = 32 * w + rt * 16 + lq * 4 + i;
            *(__bf16*)((char*)Ps + row * 128 +
                       (((c4 * 2 + (lr >> 3)) ^ (row & 7)) << 4) +
                       (lr & 7) * 2) = (__bf16)e;
          }
      }
      #pragma unroll
      for (int ks = 0; ks < 2; ++ks) {        // PV for this half
        bf16x8 pa2[2];
        #pragma unroll
        for (int rt = 0; rt < 2; ++rt) {
          int row = 32 * w + rt * 16 + lr;
          pa2[rt] = *(const bf16x8*)((char*)Ps + row * 128 +
                                     (((ks * 4 + lq) ^ (row & 7)) << 4));
        }
        #pragma unroll
        for (int c2 = 0; c2 < 4; ++c2) {
          int vrow = c2 * 16 + lr;
          bf16x8 vf = *(const bf16x8*)((char*)Vt + vrow * 256 +
                        (((h * 8 + ks * 4 + lq) << 4) ^ ((vrow & 15) << 4)));
          #pragma unroll
          for (int rt = 0; rt < 2; ++rt)
            ctx[rt][c2] = __builtin_amdgcn_mfma_f32_16x16x32_bf16(pa2[rt], vf, ctx[rt][c2], 0, 0, 0);
        }
      }
    }
  }

  #pragma unroll
  for (int rt = 0; rt < 2; ++rt)              // row sums over 16 lr-lanes
    #pragma unroll
    for (int i = 0; i < 4; ++i) {
      float v = rs[rt][i];
      v += __shfl_xor(v, 1);
      v += __shfl_xor(v, 2);
      v += __shfl_xor(v, 4);
      v += __shfl_xor(v, 8);
      rs[rt][i] = 1.0f / fmaxf(v, 2e-15f);    // clip(sum, 2e-15) per reference
    }

  #pragma unroll
  for (int rt = 0; rt < 2; ++rt)
    #pragma unroll
    for (int c2 = 0; c2 < 4; ++c2)
      #pragma unroll
      for (int i = 0; i < 4; ++i) {
        int row = qt * 128 + 32 * w + rt * 16 + lq * 4 + i;
        ctxb[gbase + (size_t)row * 64 + c2 * 16 + lr] =
            (__bf16)(ctx[rt][c2][i] * rs[rt][i]);
      }
}

// ------------------------------------------------------------- layernorm
__global__ __launch_bounds__(256) void ln_kernel(
    const float* __restrict__ O, const float* __restrict__ resid,
    const float* __restrict__ gam, const float* __restrict__ bet,
    float* __restrict__ out)
{
  const int row = blockIdx.x;
  const int tid = threadIdx.x;
  const float* orow = O + (size_t)row * 1024;
  const float* rrow = resid + (size_t)row * 1024;
  float x[4];
  float sum = 0.f, sq = 0.f;
  #pragma unroll
  for (int j = 0; j < 4; ++j) {
    int c = tid + j * 256;
    x[j] = orow[c] + rrow[c];
    sum += x[j];
    sq  += x[j] * x[j];
  }
  #pragma unroll
  for (int off = 32; off > 0; off >>= 1) {
    sum += __shfl_down(sum, off, 64);
    sq  += __shfl_down(sq, off, 64);
  }
  __shared__ float s1[4], s2[4];
  __shared__ float mean_s, inv_s;
  if ((tid & 63) == 0) { s1[tid >> 6] = sum; s2[tid >> 6] = sq; }
  __syncthreads();
  if (tid == 0) {
    float S = s1[0] + s1[1] + s1[2] + s1[3];
    float Q = s2[0] + s2[1] + s2[2] + s2[3];
    float mean = S * (1.0f / 1024.0f);
    float var  = fmaxf(Q * (1.0f / 1024.0f) - mean * mean, 0.0f);
    mean_s = mean;
    inv_s  = rsqrtf(var + 1e-5f);
  }
  __syncthreads();
  float mean = mean_s, inv = inv_s;
  #pragma unroll
  for (int j = 0; j < 4; ++j) {
    int c = tid + j * 256;
    out[(size_t)row * 1024 + c] = (x[j] - mean) * inv * gam[c] + bet[c];
  }
}

extern "C" void kernel_launch(void* const* d_in, const int* in_sizes, int n_in,
                              void* d_out, int out_size, void* d_ws, size_t ws_size,
                              hipStream_t stream)
{
  const float* query = (const float*)d_in[0];
  const float* keyi  = (const float*)d_in[1];
  const float* value = (const float*)d_in[2];
  const float* qmask = (const float*)d_in[3];
  const float* kmask = (const float*)d_in[4];
  const float* Wq = (const float*)d_in[5];
  const float* bq = (const float*)d_in[6];
  const float* Wk = (const float*)d_in[7];
  const float* bk = (const float*)d_in[8];
  const float* Wv = (const float*)d_in[9];
  const float* bv = (const float*)d_in[10];
  const float* Wo = (const float*)d_in[11];
  const float* bo = (const float*)d_in[12];
  const float* gam = (const float*)d_in[13];
  const float* bet = (const float*)d_in[14];

  char* ws = (char*)d_ws;
  __bf16* qbuf = (__bf16*)(ws);
  __bf16* kbuf = (__bf16*)(ws + ((size_t)16 << 20));
  __bf16* vbuf = (__bf16*)(ws + ((size_t)32 << 20));
  __bf16* wb   = (__bf16*)(ws + ((size_t)48 << 20));
  float*  obuf = (float*)(ws + ((size_t)16 << 20));
  __bf16* abuf = (__bf16*)(ws + ((size_t)56 << 20));  // 48 MB, main path only

  const bool big = ws_size >= ((size_t)104 << 20);

  Cvt4 cv;
  cv.src[0] = Wq; cv.src[1] = Wk; cv.src[2] = Wv; cv.src[3] = Wo;
  cv.dst = wb;

  dim3 tb(256);
  hipLaunchKernelGGL(cvt_w, dim3(1024, 4), tb, 0, stream, cv);

  if (big) {
    Cvt3 ca;
    ca.src[0] = query; ca.src[1] = keyi; ca.src[2] = value;
    ca.dst = abuf;
    hipLaunchKernelGGL(cvt_a, dim3(4096, 3), tb, 0, stream, ca);

    G8 gq;
    gq.A[0] = abuf;
    gq.A[1] = abuf + ((size_t)8 << 20);
    gq.A[2] = abuf + ((size_t)16 << 20);
    gq.W[0] = wb; gq.W[1] = wb + (size_t)KK * NN; gq.W[2] = wb + (size_t)2 * KK * NN;
    gq.bias[0] = bq; gq.bias[1] = bk; gq.bias[2] = bv;
    gq.C[0] = qbuf; gq.C[1] = kbuf; gq.C[2] = vbuf;
    hipLaunchKernelGGL((gemm8p<true>), dim3(32, 4, 3), dim3(512), 0, stream, gq);
  } else {
    GQKV qkv;
    qkv.A[0] = query; qkv.A[1] = keyi; qkv.A[2] = value;
    qkv.W = wb;
    qkv.bias[0] = bq; qkv.bias[1] = bk; qkv.bias[2] = bv;
    qkv.C[0] = qbuf;  qkv.C[1] = kbuf; qkv.C[2] = vbuf;
    hipLaunchKernelGGL(gemm_qkv, dim3(64, 8, 3), tb, 0, stream, qkv);
  }

  hipLaunchKernelGGL(attn_kernel, dim3(8, 128), tb, 0, stream,
                     qbuf, kbuf, vbuf, qmask, kmask, qbuf);

  G8 go;
  go.A[0] = qbuf;                      // ctx (bf16, in-place over qbuf)
  go.W[0] = wb + (size_t)3 * KK * NN;  // Wo bf16
  go.bias[0] = bo;
  go.C[0] = obuf;
  go.A[1] = go.A[2] = go.A[0]; go.W[1] = go.W[2] = go.W[0];
  go.bias[1] = go.bias[2] = go.bias[0]; go.C[1] = go.C[2] = go.C[0];
  hipLaunchKernelGGL((gemm8p<false>), dim3(32, 4, 1), dim3(512), 0, stream, go);

  hipLaunchKernelGGL(ln_kernel, dim3(8192), tb, 0, stream,
                     obuf, query, gam, bet, (float*)d_out);
}

// Round 4
// 353.713 us; speedup vs baseline: 1.8453x; 1.1681x over previous
//
#include <hip/hip_runtime.h>
#include <hip/hip_bf16.h>

// MultiHeadAttention: B=8, L=1024, D=1024, H=16, dh=64. fp32 in/out.
// Round 10: attn latency fixes. (a) K staging back to global_load_lds DMA
// with PRE-SWIZZLED global source (linear LDS dest, XOR'd read) — removes
// the round-3 reg round-trip that cost +9us. (b) P-write XOR key fixed to
// lq<<1 (was row&7; lanes lq/lq+2 aliased -> the residual 2.16M conflicts).
// (c) device-computed g_nomask flag: all-ones masks skip the per-element
// kms read + select (masked path kept for correctness). (d) cvt_w+cvt_a+
// mask-flag fused into one prep kernel (7 -> 5 launches). (e) setprio
// around attn MFMA clusters. GEMMs unchanged (256^2 8-phase).
//
// Pipeline (5 launches):
//  1) prep grid(16385): W->bf16, QKV->bf16, mask flag
//  2) gemm8p<true>  grid(32,4,3): 8-phase GEMM -> q/k/v (bf16, +bias)
//  3) attn grid(8,128): ctx written in-place over qbuf
//  4) gemm8p<false> grid(32,4,1): ctx @ Wo^T + bo -> obuf (fp32)
//  5) ln: LayerNorm(query + O) -> d_out
// ws: qbuf[0,16M) kbuf[16,32M) vbuf[32,48M) W4[48,56M) obuf[16,48M)
//     abuf[56,104M).  Fallback if ws < 104MB: old fp32-A gemm_qkv, no cvt_a.

typedef __bf16 bf16x8 __attribute__((ext_vector_type(8)));
typedef float  f32x4  __attribute__((ext_vector_type(4)));

#define KK 1024
#define NN 1024

union BfPack4 { __bf16 h[4]; uint2 u; };
union BfPack8 { __bf16 h[8]; uint4 u; };

__device__ int g_nomask;

// async global->LDS, 16 B/lane. LDS dest = wave-uniform base + lane*16.
__device__ __forceinline__ void lds_copy16(void* lds, const void* gsrc) {
  __builtin_amdgcn_global_load_lds(
      (__attribute__((address_space(1))) void*)(uintptr_t)gsrc,
      (__attribute__((address_space(3))) void*)(unsigned int)(uintptr_t)lds,
      16, 0, 0);
}

// ------------------------------------------------- fused prep kernel
// blocks [0,12288): QKV fp32->bf16 (3 x 4096)   [skipped if !do_a]
// blocks [12288,16384): W fp32->bf16 (4 x 1024)
// block 16384: mask all-ones check -> g_nomask
struct Prep {
  const float* wsrc[4]; __bf16* wdst;
  const float* asrc[3]; __bf16* adst; int do_a;
  const float* qm; const float* km;
};

__global__ __launch_bounds__(256) void prep_kernel(Prep a) {
  const int bid = blockIdx.x;
  const int tid = threadIdx.x;
  if (bid < 12288) {                       // cvt_a
    if (!a.do_a) return;
    const int z = bid >> 12, i = bid & 4095;
    const float* s = a.asrc[z];
    __bf16* d = a.adst + (size_t)z * ((size_t)8 << 20);
    const size_t off = ((size_t)i * 256 + tid) * 8;
    float4 f0 = *(const float4*)&s[off];
    float4 f1 = *(const float4*)&s[off + 4];
    BfPack8 p;
    p.h[0] = (__bf16)f0.x; p.h[1] = (__bf16)f0.y;
    p.h[2] = (__bf16)f0.z; p.h[3] = (__bf16)f0.w;
    p.h[4] = (__bf16)f1.x; p.h[5] = (__bf16)f1.y;
    p.h[6] = (__bf16)f1.z; p.h[7] = (__bf16)f1.w;
    *(uint4*)&d[off] = p.u;
  } else if (bid < 16384) {                // cvt_w
    const int b = bid - 12288;
    const int z = b >> 10, i = b & 1023;
    const float* s = a.wsrc[z];
    __bf16* d = a.wdst + (size_t)z * (KK * NN);
    const int idx = (i * 256 + tid) * 4;
    float4 f = *(const float4*)&s[idx];
    BfPack4 p;
    p.h[0] = (__bf16)f.x; p.h[1] = (__bf16)f.y;
    p.h[2] = (__bf16)f.z; p.h[3] = (__bf16)f.w;
    *(uint2*)&d[idx] = p.u;
  } else {                                 // mask flag
    int ok = 1;
    for (int i = tid; i < 8192; i += 256)
      ok &= (a.qm[i] != 0.f) & (a.km[i] != 0.f);
    const int all_ok = __syncthreads_and(ok);
    if (tid == 0) g_nomask = all_ok;
  }
}

// --------------------------------------------- 256x256 8-phase bf16 GEMM
struct G8 {
  const __bf16* A[3];
  const __bf16* W[3];
  const float*  bias[3];
  void*         C[3];
};

#define BAR()   __builtin_amdgcn_s_barrier()
#define PRIO(x) __builtin_amdgcn_s_setprio(x)
#define WAIT_LGKM0() do { asm volatile("s_waitcnt lgkmcnt(0)" ::: "memory"); \
                          __builtin_amdgcn_sched_barrier(0); } while (0)
#define WAIT_VM4()  asm volatile("s_waitcnt vmcnt(4)" ::: "memory")
#define WAIT_VM0()  asm volatile("s_waitcnt vmcnt(0)" ::: "memory")

#define STAGE_A(buf, half, kt) do {                                          \
  lds_copy16(smem + (buf)*32768 + (half)*16384 + ldsW,                       \
             pA0[half] + (size_t)(kt)*64);                                   \
  lds_copy16(smem + (buf)*32768 + (half)*16384 + ldsW + 1024,                \
             pA1[half] + (size_t)(kt)*64); } while (0)

#define STAGE_B(buf, half, kt) do {                                          \
  lds_copy16(smem + 65536 + (buf)*32768 + (half)*16384 + ldsW,               \
             pB0[half] + (size_t)(kt)*64);                                   \
  lds_copy16(smem + 65536 + (buf)*32768 + (half)*16384 + ldsW + 1024,        \
             pB1[half] + (size_t)(kt)*64); } while (0)

#define LDA(buf, mh) do {                                                    \
  const char* _p = aSelf + (buf)*32768 + (mh)*8192;                          \
  _Pragma("unroll") for (int i_ = 0; i_ < 4; ++i_) {                         \
    af[i_][0] = *(const bf16x8*)(_p + i_*2048 + c0_);                        \
    af[i_][1] = *(const bf16x8*)(_p + i_*2048 + c1_); } } while (0)

#define LDB(buf, nh) do {                                                    \
  const char* _p = bSelf + (buf)*32768 + (nh)*4096;                          \
  _Pragma("unroll") for (int j_ = 0; j_ < 2; ++j_) {                         \
    bf[(nh)*2 + j_][0] = *(const bf16x8*)(_p + j_*2048 + c0_);               \
    bf[(nh)*2 + j_][1] = *(const bf16x8*)(_p + j_*2048 + c1_); } } while (0)

#define MM(mh, nh) do {                                                      \
  _Pragma("unroll") for (int i_ = 0; i_ < 4; ++i_)                           \
  _Pragma("unroll") for (int j_ = 0; j_ < 2; ++j_) {                         \
    acc[(mh)*4+i_][(nh)*2+j_] = __builtin_amdgcn_mfma_f32_16x16x32_bf16(     \
        af[i_][0], bf[(nh)*2+j_][0], acc[(mh)*4+i_][(nh)*2+j_], 0, 0, 0);    \
    acc[(mh)*4+i_][(nh)*2+j_] = __builtin_amdgcn_mfma_f32_16x16x32_bf16(     \
        af[i_][1], bf[(nh)*2+j_][1], acc[(mh)*4+i_][(nh)*2+j_], 0, 0, 0);    \
  } } while (0)

template <bool OUT_BF16>
__global__ __launch_bounds__(512, 2) void gemm8p(G8 args)
{
  __shared__ __align__(16) char smem[131072];
  const int z = blockIdx.z;
  const __bf16* __restrict__ A    = args.A[z];
  const __bf16* __restrict__ W    = args.W[z];
  const float*  __restrict__ bias = args.bias[z];

  const int tid = threadIdx.x;
  const int l = tid & 63, w = tid >> 6;
  const int lr = l & 15, lq = l >> 4;
  const int wr = w >> 2, wc = w & 3;          // 2M x 4N waves

  // XCD-aware swizzle over the 128 (m,n) tiles (128 % 8 == 0 -> bijective)
  int lin = blockIdx.y * 32 + blockIdx.x;
  lin = (lin & 7) * 16 + (lin >> 3);
  const int m0 = (lin & 31) * 256;
  const int n0 = (lin >> 5) * 256;

  const int s0 = w * 128 + l, s1 = s0 + 64;
  const int r0 = s0 >> 3, kq0 = (s0 & 7) ^ (r0 & 7);
  const int r1 = s1 >> 3, kq1 = (s1 & 7) ^ (r1 & 7);
  const __bf16* pA0[2]; const __bf16* pA1[2];
  const __bf16* pB0[2]; const __bf16* pB1[2];
  #pragma unroll
  for (int h = 0; h < 2; ++h) {
    pA0[h] = A + (size_t)(m0 + h * 128 + r0) * KK + kq0 * 8;
    pA1[h] = A + (size_t)(m0 + h * 128 + r1) * KK + kq1 * 8;
    pB0[h] = W + (size_t)(n0 + h * 128 + r0) * KK + kq0 * 8;
    pB1[h] = W + (size_t)(n0 + h * 128 + r1) * KK + kq1 * 8;
  }
  const int ldsW = w * 2048;

  const int aRow = lr * 128;
  const int c0_ = ((lq)     ^ (lr & 7)) * 16;
  const int c1_ = ((4 + lq) ^ (lr & 7)) * 16;
  const char* aSelf = smem + wr * 16384 + aRow;
  const char* bSelf = smem + 65536 + (wc >> 1) * 16384 + (wc & 1) * 8192 + aRow;

  bf16x8 af[4][2], bf[4][2];
  f32x4 acc[8][4] = {};

  STAGE_A(0, 0, 0); STAGE_A(0, 1, 0);
  STAGE_B(0, 0, 0); STAGE_B(0, 1, 0);
  STAGE_B(1, 0, 1); STAGE_B(1, 1, 1);
  WAIT_VM4();
  BAR();

  for (int it = 0; it < 8; ++it) {
    const int t2 = it * 2;
    LDA(0, 0); LDB(0, 0);
    STAGE_A(1, 0, t2 + 1);
    BAR(); WAIT_LGKM0();
    PRIO(1); MM(0, 0); PRIO(0);
    BAR();
    LDB(0, 1);
    STAGE_A(1, 1, t2 + 1);
    BAR(); WAIT_LGKM0();
    PRIO(1); MM(0, 1); PRIO(0);
    BAR();
    LDA(0, 1);
    if (it < 7) STAGE_B(0, 0, t2 + 2);
    BAR(); WAIT_LGKM0();
    PRIO(1); MM(1, 0); PRIO(0);
    BAR();
    if (it < 7) { STAGE_B(0, 1, t2 + 2); WAIT_VM4(); }
    else        { WAIT_VM0(); }
    BAR();
    PRIO(1); MM(1, 1); PRIO(0);
    BAR();
    LDA(1, 0); LDB(1, 0);
    if (it < 7) STAGE_A(0, 0, t2 + 2);
    BAR(); WAIT_LGKM0();
    PRIO(1); MM(0, 0); PRIO(0);
    BAR();
    LDB(1, 1);
    if (it < 7) STAGE_A(0, 1, t2 + 2);
    BAR(); WAIT_LGKM0();
    PRIO(1); MM(0, 1); PRIO(0);
    BAR();
    LDA(1, 1);
    if (it < 7) STAGE_B(1, 0, t2 + 3);
    BAR(); WAIT_LGKM0();
    PRIO(1); MM(1, 0); PRIO(0);
    BAR();
    if (it < 7) { STAGE_B(1, 1, t2 + 3); WAIT_VM4(); }
    BAR();
    PRIO(1); MM(1, 1); PRIO(0);
    BAR();
  }

  float bv[4];
  #pragma unroll
  for (int n = 0; n < 4; ++n) bv[n] = bias[n0 + wc * 64 + n * 16 + lr];

  #pragma unroll
  for (int f = 0; f < 8; ++f) {
    const int gm = m0 + wr * 128 + f * 16 + lq * 4;
    #pragma unroll
    for (int n = 0; n < 4; ++n) {
      const int gn = n0 + wc * 64 + n * 16 + lr;
      #pragma unroll
      for (int i = 0; i < 4; ++i) {
        const float v = acc[f][n][i] + bv[n];
        if constexpr (OUT_BF16)
          ((__bf16*)args.C[z])[(size_t)(gm + i) * NN + gn] = (__bf16)v;
        else
          ((float*)args.C[z])[(size_t)(gm + i) * NN + gn] = v;
      }
    }
  }
}

// ------------------------------------- fallback fp32-A QKV GEMM (old path)
struct GQKV {
  const float*  A[3];
  const __bf16* W;
  const float*  bias[3];
  __bf16*       C[3];
};

__global__ __launch_bounds__(256) void gemm_qkv(GQKV args)
{
  __shared__ alignas(16) __bf16 As[128 * 40];
  __shared__ alignas(16) __bf16 Bs[2][4096];
  const int z = blockIdx.z;
  const float*  A    = args.A[z];
  const __bf16* W    = args.W + (size_t)z * KK * NN;
  const float*  bias = args.bias[z];
  __bf16* C = args.C[z];
  const int tid = threadIdx.x, l = tid & 63, w = tid >> 6;
  const int m0 = blockIdx.x * 128, n0 = blockIdx.y * 128;
  const int lr = l & 15, lq = l >> 4;
  const int wm = (w & 1) * 64, wn = (w >> 1) * 64;

  const __bf16* gw0 = &W[(size_t)(n0 + (tid >> 2)) * KK + (tid & 3) * 8];
  const __bf16* gw1 = &W[(size_t)(n0 + 64 + (tid >> 2)) * KK + (tid & 3) * 8];

  float4 pa[4];
  #pragma unroll
  for (int s = 0; s < 4; ++s) {
    int c = tid + 256 * s; int row = c >> 3, ko = (c & 7) * 4;
    pa[s] = *(const float4*)&A[(size_t)(m0 + row) * KK + ko];
  }
  lds_copy16((char*)Bs + w * 1024,        gw0);
  lds_copy16((char*)Bs + 4096 + w * 1024, gw1);

  f32x4 acc[4][4] = {};
  int ib = 0;
  for (int kk = 0; kk < KK; kk += 32) {
    __syncthreads();
    #pragma unroll
    for (int s = 0; s < 4; ++s) {
      int c = tid + 256 * s; int row = c >> 3, ko = (c & 7) * 4;
      BfPack4 p;
      p.h[0] = (__bf16)pa[s].x; p.h[1] = (__bf16)pa[s].y;
      p.h[2] = (__bf16)pa[s].z; p.h[3] = (__bf16)pa[s].w;
      *(uint2*)&As[row * 40 + ko] = p.u;
    }
    __syncthreads();
    if (kk + 32 < KK) {
      lds_copy16((char*)Bs + (ib ^ 1) * 8192 + w * 1024,        gw0 + kk + 32);
      lds_copy16((char*)Bs + (ib ^ 1) * 8192 + 4096 + w * 1024, gw1 + kk + 32);
      #pragma unroll
      for (int s = 0; s < 4; ++s) {
        int c = tid + 256 * s; int row = c >> 3, ko = (c & 7) * 4;
        pa[s] = *(const float4*)&A[(size_t)(m0 + row) * KK + kk + 32 + ko];
      }
    }
    const __bf16* Bb = (const __bf16*)((char*)Bs + ib * 8192);
    bf16x8 af2[4], bf2[4];
    #pragma unroll
    for (int t = 0; t < 4; ++t) {
      af2[t] = *(const bf16x8*)&As[(wm + t * 16 + lr) * 40 + lq * 8];
      bf2[t] = *(const bf16x8*)&Bb[(wn + t * 16 + lr) * 32 + lq * 8];
    }
    #pragma unroll
    for (int mt = 0; mt < 4; ++mt)
      #pragma unroll
      for (int nt = 0; nt < 4; ++nt)
        acc[mt][nt] = __builtin_amdgcn_mfma_f32_16x16x32_bf16(af2[mt], bf2[nt], acc[mt][nt], 0, 0, 0);
    ib ^= 1;
  }

  #pragma unroll
  for (int mt = 0; mt < 4; ++mt)
    #pragma unroll
    for (int nt = 0; nt < 4; ++nt)
      #pragma unroll
      for (int i = 0; i < 4; ++i) {
        int gm = m0 + wm + mt * 16 + lq * 4 + i;
        int gn = n0 + wn + nt * 16 + lr;
        C[(size_t)gm * NN + gn] = (__bf16)(acc[mt][nt][i] + bias[gn]);
      }
}

// ------------------------------------------------------------- attention
// Block = (q-tile 128, head-slab g); wave w owns q-rows [32w,32w+32).
// Grid remap: the 8 q-tile blocks of slab g land on ONE XCD (K/V L2 reuse).
// K staged via global_load_lds DMA with pre-swizzled SOURCE (linear LDS
// dest; slot kq holds logical kq^(r&3); read applies same XOR). V reg-
// prefetched one tile ahead, transposed into XOR'd V^T. P granule key =
// lq<<1 (write) / (lr>>2)<<1 (read) -> bank-uniform b16 writes AND b128
// reads. Mask fast path via g_nomask. Plain __launch_bounds__(256) (a
// min-occupancy hint caps VGPR at 84 and spills — round-8 post-mortem).
__global__ __launch_bounds__(256) void attn_kernel(
    const __bf16* __restrict__ qb, const __bf16* __restrict__ kb,
    const __bf16* __restrict__ vb, const float* __restrict__ qm,
    const float* __restrict__ km, __bf16* __restrict__ ctxb)
{
  const int g  = blockIdx.x * 16 + (blockIdx.y >> 3);   // 0..127
  const int qt = blockIdx.y & 7;                        // 0..7
  const int tid = threadIdx.x, l = tid & 63, w = tid >> 6;
  const int lr = l & 15, lq = l >> 4;

  __shared__ alignas(16) __bf16 Ps[128 * 64];      // P (XOR); Q prologue
  __shared__ alignas(16) __bf16 Ks[2 * 128 * 32];  // K panels (src-XOR DMA)
  __shared__ alignas(16) __bf16 Vt[64 * 128];      // V^T (XOR)
  __shared__ alignas(16) __bf16 kms[1024];         // k-mask gate bits

  const size_t gbase = (size_t)g * (1024 * 64);
  const __bf16* qg = qb + gbase;
  const __bf16* kg = kb + gbase;
  const __bf16* vg = vb + gbase;
  const float* qmrow = qm + (size_t)(g & 7) * 1024;
  const float* kmrow = km + (size_t)(g & 7) * 1024;
  const int nm = g_nomask;

  // ---- prologue ----
  #pragma unroll
  for (int s = 0; s < 4; ++s) {               // Q 128x64 async into Ps region
    int c = tid + 256 * s;
    int p = c >> 9, r = (c >> 2) & 127, q0 = c & 3;
    lds_copy16((char*)Ps + w * 1024 + s * 4096,
               &qg[(size_t)(qt * 128 + r) * 64 + p * 32 + q0 * 8]);
  }
  {                                           // mask gate bits (nonzero-ness)
    float4 kf = *(const float4*)&kmrow[tid * 4];
    BfPack4 p;
    p.h[0] = (__bf16)(kf.x == 0.f ? 0.f : 1.f);
    p.h[1] = (__bf16)(kf.y == 0.f ? 0.f : 1.f);
    p.h[2] = (__bf16)(kf.z == 0.f ? 0.f : 1.f);
    p.h[3] = (__bf16)(kf.w == 0.f ? 0.f : 1.f);
    *(uint2*)&kms[tid * 4] = p.u;
  }
  float qmv[2][4];
  #pragma unroll
  for (int rt = 0; rt < 2; ++rt)
    #pragma unroll
    for (int i = 0; i < 4; ++i)
      qmv[rt][i] = qmrow[qt * 128 + 32 * w + rt * 16 + lq * 4 + i];

  // K DMA source offsets (pre-swizzled column so LDS slot kq holds
  // logical kq ^ (r&3); LDS dest stays linear = chunk*16).
  int gkOff[4];
  #pragma unroll
  for (int s = 0; s < 4; ++s) {
    int c = tid + 256 * s;
    int p = c >> 9, r = (c >> 2) & 127, q0 = c & 3;
    gkOff[s] = r * 64 + p * 32 + ((q0 ^ (r & 3)) * 8);
  }

  __syncthreads();

  bf16x8 qa[2][2];                            // Q frags, pinned all 8 iters
  #pragma unroll
  for (int rt = 0; rt < 2; ++rt)
    #pragma unroll
    for (int p = 0; p < 2; ++p)
      qa[rt][p] = *(const bf16x8*)((char*)Ps + p * 8192 +
                                   (32 * w + rt * 16 + lr) * 64 + lq * 16);

  uint4 pv[4];                                // V prefetch (tile 0)
  #pragma unroll
  for (int s = 0; s < 4; ++s) {
    int ch = tid + 256 * s; int j = ch & 127, c0 = ch >> 7;
    pv[s] = *(const uint4*)&vg[(size_t)j * 64 + c0 * 8];
  }

  const int kKey = (lq ^ (lr & 3)) << 4;      // K read granule offset
  const int pwKey = (lq << 1);                // P write granule XOR
  const int prKey = ((lr >> 2) << 1);         // P read granule XOR
  float rs[2][4] = {};
  f32x4 ctx[2][4] = {};

  for (int kt = 0; kt < 8; ++kt) {
    __syncthreads();                          // barrier-1: prev compute done
    #pragma unroll
    for (int s = 0; s < 4; ++s)               // K async DMA (pre-swizzled src)
      lds_copy16((char*)Ks + w * 1024 + s * 4096,
                 kg + (size_t)kt * 8192 + gkOff[s]);
    #pragma unroll
    for (int s = 0; s < 4; ++s) {             // V^T from prefetched regs
      int ch = tid + 256 * s; int j = ch & 127, c0 = ch >> 7;
      BfPack8 vv; vv.u = pv[s];
      const int jhi = (j >> 3) << 4, jlo = (j & 7) * 2;
      #pragma unroll
      for (int cc = 0; cc < 8; ++cc) {
        int row = c0 * 8 + cc;
        *(__bf16*)((char*)Vt + row * 256 + (jhi ^ ((row & 15) << 4)) + jlo) =
            vv.h[cc];
      }
    }
    __syncthreads();                          // barrier-2: staging visible
    if (kt < 7) {                             // V prefetch for next tile
      #pragma unroll
      for (int s = 0; s < 4; ++s) {
        int ch = tid + 256 * s; int j = ch & 127, c0 = ch >> 7;
        pv[s] = *(const uint4*)&vg[(size_t)((kt + 1) * 128 + j) * 64 + c0 * 8];
      }
    }
    #pragma unroll
    for (int h = 0; h < 2; ++h) {             // two 64-j halves
      f32x4 sacc[2][4];
      PRIO(1);
      #pragma unroll
      for (int c4 = 0; c4 < 4; ++c4) {        // S = Q K^T
        int ct = h * 4 + c4;
        bf16x8 kb0 = *(const bf16x8*)((char*)Ks + (ct * 16 + lr) * 64 + kKey);
        bf16x8 kb1 = *(const bf16x8*)((char*)Ks + 8192 + (ct * 16 + lr) * 64 + kKey);
        #pragma unroll
        for (int rt = 0; rt < 2; ++rt) {
          f32x4 zz = {};
          zz = __builtin_amdgcn_mfma_f32_16x16x32_bf16(qa[rt][0], kb0, zz, 0, 0, 0);
          sacc[rt][c4] = __builtin_amdgcn_mfma_f32_16x16x32_bf16(qa[rt][1], kb1, zz, 0, 0, 0);
        }
      }
      PRIO(0);
      if (nm) {                               // fast path: no masking
        #pragma unroll
        for (int c4 = 0; c4 < 4; ++c4)
          #pragma unroll
          for (int rt = 0; rt < 2; ++rt)
            #pragma unroll
            for (int i = 0; i < 4; ++i) {
              float e = __expf(sacc[rt][c4][i] * 0.125f);
              rs[rt][i] += e;
              int row = 32 * w + rt * 16 + lq * 4 + i;
              *(__bf16*)((char*)Ps + row * 128 +
                         (((c4 * 2 + (lr >> 3)) ^ pwKey) << 4) +
                         (lr & 7) * 2) = (__bf16)e;
            }
      } else {
        #pragma unroll
        for (int c4 = 0; c4 < 4; ++c4) {
          int ct = h * 4 + c4;
          float kmv = (float)kms[kt * 128 + ct * 16 + lr];
          #pragma unroll
          for (int rt = 0; rt < 2; ++rt)
            #pragma unroll
            for (int i = 0; i < 4; ++i) {
              float e = (qmv[rt][i] * kmv == 0.f) ? 0.f
                                                  : __expf(sacc[rt][c4][i] * 0.125f);
              rs[rt][i] += e;
              int row = 32 * w + rt * 16 + lq * 4 + i;
              *(__bf16*)((char*)Ps + row * 128 +
                         (((c4 * 2 + (lr >> 3)) ^ pwKey) << 4) +
                         (lr & 7) * 2) = (__bf16)e;
            }
        }
      }
      PRIO(1);
      #pragma unroll
      for (int ks = 0; ks < 2; ++ks) {        // PV for this half
        bf16x8 pa2[2];
        #pragma unroll
        for (int rt = 0; rt < 2; ++rt) {
          int row = 32 * w + rt * 16 + lr;
          pa2[rt] = *(const bf16x8*)((char*)Ps + row * 128 +
                                     (((ks * 4 + lq) ^ prKey) << 4));
        }
        #pragma unroll
        for (int c2 = 0; c2 < 4; ++c2) {
          int vrow = c2 * 16 + lr;
          bf16x8 vf = *(const bf16x8*)((char*)Vt + vrow * 256 +
                        (((h * 8 + ks * 4 + lq) << 4) ^ ((vrow & 15) << 4)));
          #pragma unroll
          for (int rt = 0; rt < 2; ++rt)
            ctx[rt][c2] = __builtin_amdgcn_mfma_f32_16x16x32_bf16(pa2[rt], vf, ctx[rt][c2], 0, 0, 0);
        }
      }
      PRIO(0);
    }
  }

  #pragma unroll
  for (int rt = 0; rt < 2; ++rt)              // row sums over 16 lr-lanes
    #pragma unroll
    for (int i = 0; i < 4; ++i) {
      float v = rs[rt][i];
      v += __shfl_xor(v, 1);
      v += __shfl_xor(v, 2);
      v += __shfl_xor(v, 4);
      v += __shfl_xor(v, 8);
      rs[rt][i] = 1.0f / fmaxf(v, 2e-15f);    // clip(sum, 2e-15) per reference
    }

  #pragma unroll
  for (int rt = 0; rt < 2; ++rt)
    #pragma unroll
    for (int c2 = 0; c2 < 4; ++c2)
      #pragma unroll
      for (int i = 0; i < 4; ++i) {
        int row = qt * 128 + 32 * w + rt * 16 + lq * 4 + i;
        ctxb[gbase + (size_t)row * 64 + c2 * 16 + lr] =
            (__bf16)(ctx[rt][c2][i] * rs[rt][i]);
      }
}

// ------------------------------------------------------------- layernorm
__global__ __launch_bounds__(256) void ln_kernel(
    const float* __restrict__ O, const float* __restrict__ resid,
    const float* __restrict__ gam, const float* __restrict__ bet,
    float* __restrict__ out)
{
  const int row = blockIdx.x;
  const int tid = threadIdx.x;
  const float* orow = O + (size_t)row * 1024;
  const float* rrow = resid + (size_t)row * 1024;
  float x[4];
  float sum = 0.f, sq = 0.f;
  #pragma unroll
  for (int j = 0; j < 4; ++j) {
    int c = tid + j * 256;
    x[j] = orow[c] + rrow[c];
    sum += x[j];
    sq  += x[j] * x[j];
  }
  #pragma unroll
  for (int off = 32; off > 0; off >>= 1) {
    sum += __shfl_down(sum, off, 64);
    sq  += __shfl_down(sq, off, 64);
  }
  __shared__ float s1[4], s2[4];
  __shared__ float mean_s, inv_s;
  if ((tid & 63) == 0) { s1[tid >> 6] = sum; s2[tid >> 6] = sq; }
  __syncthreads();
  if (tid == 0) {
    float S = s1[0] + s1[1] + s1[2] + s1[3];
    float Q = s2[0] + s2[1] + s2[2] + s2[3];
    float mean = S * (1.0f / 1024.0f);
    float var  = fmaxf(Q * (1.0f / 1024.0f) - mean * mean, 0.0f);
    mean_s = mean;
    inv_s  = rsqrtf(var + 1e-5f);
  }
  __syncthreads();
  float mean = mean_s, inv = inv_s;
  #pragma unroll
  for (int j = 0; j < 4; ++j) {
    int c = tid + j * 256;
    out[(size_t)row * 1024 + c] = (x[j] - mean) * inv * gam[c] + bet[c];
  }
}

extern "C" void kernel_launch(void* const* d_in, const int* in_sizes, int n_in,
                              void* d_out, int out_size, void* d_ws, size_t ws_size,
                              hipStream_t stream)
{
  const float* query = (const float*)d_in[0];
  const float* keyi  = (const float*)d_in[1];
  const float* value = (const float*)d_in[2];
  const float* qmask = (const float*)d_in[3];
  const float* kmask = (const float*)d_in[4];
  const float* Wq = (const float*)d_in[5];
  const float* bq = (const float*)d_in[6];
  const float* Wk = (const float*)d_in[7];
  const float* bk = (const float*)d_in[8];
  const float* Wv = (const float*)d_in[9];
  const float* bv = (const float*)d_in[10];
  const float* Wo = (const float*)d_in[11];
  const float* bo = (const float*)d_in[12];
  const float* gam = (const float*)d_in[13];
  const float* bet = (const float*)d_in[14];

  char* ws = (char*)d_ws;
  __bf16* qbuf = (__bf16*)(ws);
  __bf16* kbuf = (__bf16*)(ws + ((size_t)16 << 20));
  __bf16* vbuf = (__bf16*)(ws + ((size_t)32 << 20));
  __bf16* wb   = (__bf16*)(ws + ((size_t)48 << 20));
  float*  obuf = (float*)(ws + ((size_t)16 << 20));
  __bf16* abuf = (__bf16*)(ws + ((size_t)56 << 20));  // 48 MB, main path only

  const bool big = ws_size >= ((size_t)104 << 20);

  Prep pp;
  pp.wsrc[0] = Wq; pp.wsrc[1] = Wk; pp.wsrc[2] = Wv; pp.wsrc[3] = Wo;
  pp.wdst = wb;
  pp.asrc[0] = query; pp.asrc[1] = keyi; pp.asrc[2] = value;
  pp.adst = abuf; pp.do_a = big ? 1 : 0;
  pp.qm = qmask; pp.km = kmask;

  dim3 tb(256);
  hipLaunchKernelGGL(prep_kernel, dim3(16385), tb, 0, stream, pp);

  if (big) {
    G8 gq;
    gq.A[0] = abuf;
    gq.A[1] = abuf + ((size_t)8 << 20);
    gq.A[2] = abuf + ((size_t)16 << 20);
    gq.W[0] = wb; gq.W[1] = wb + (size_t)KK * NN; gq.W[2] = wb + (size_t)2 * KK * NN;
    gq.bias[0] = bq; gq.bias[1] = bk; gq.bias[2] = bv;
    gq.C[0] = qbuf; gq.C[1] = kbuf; gq.C[2] = vbuf;
    hipLaunchKernelGGL((gemm8p<true>), dim3(32, 4, 3), dim3(512), 0, stream, gq);
  } else {
    GQKV qkv;
    qkv.A[0] = query; qkv.A[1] = keyi; qkv.A[2] = value;
    qkv.W = wb;
    qkv.bias[0] = bq; qkv.bias[1] = bk; qkv.bias[2] = bv;
    qkv.C[0] = qbuf;  qkv.C[1] = kbuf; qkv.C[2] = vbuf;
    hipLaunchKernelGGL(gemm_qkv, dim3(64, 8, 3), tb, 0, stream, qkv);
  }

  hipLaunchKernelGGL(attn_kernel, dim3(8, 128), tb, 0, stream,
                     qbuf, kbuf, vbuf, qmask, kmask, qbuf);

  G8 go;
  go.A[0] = qbuf;                      // ctx (bf16, in-place over qbuf)
  go.W[0] = wb + (size_t)3 * KK * NN;  // Wo bf16
  go.bias[0] = bo;
  go.C[0] = obuf;
  go.A[1] = go.A[2] = go.A[0]; go.W[1] = go.W[2] = go.W[0];
  go.bias[1] = go.bias[2] = go.bias[0]; go.C[1] = go.C[2] = go.C[0];
  hipLaunchKernelGGL((gemm8p<false>), dim3(32, 4, 1), dim3(512), 0, stream, go);

  hipLaunchKernelGGL(ln_kernel, dim3(8192), tb, 0, stream,
                     obuf, query, gam, bet, (float*)d_out);
}